// Round 2
// baseline (67.993 us; speedup 1.0000x reference)
//
#include <hip/hip_runtime.h>
#include <math.h>

#define NN   96
#define NPOS (96*96)   // 9216
#define BB   32
#define KV   1024
#define KA   2048
#define PTILE 256
#define NPT  (NPOS/PTILE)  // 36

// ---------------- nb: separable DoG convolutions ----------------
// nb_f = l_ex * G_ex @ act @ G_ex^T - l_in * G_in @ act @ G_in^T
// 24 blocks: (component c in 0..5) x (j-stripe of 24 cols).
__global__ __launch_bounds__(256) void nb_kernel(
    const float* __restrict__ na_v, const float* __restrict__ na_a,
    const float* __restrict__ na_m, float* __restrict__ cpt)
{
    __shared__ float G[96][100];
    __shared__ float act_s[96][100];
    __shared__ float T1t[24][100];   // T1 transposed: T1t[j_local][h]
    const int c  = blockIdx.x >> 2;
    const int js = (blockIdx.x & 3) * 24;
    float l, s;
    if      (c == 0) { l =  1.60f; s = 3.5f;  }
    else if (c == 1) { l = -1.23f; s = 6.3f;  }
    else if (c == 2) { l =  1.00f; s = 5.3f;  }
    else if (c == 3) { l = -0.80f; s = 11.8f; }
    else if (c == 4) { l =  3.80f; s = 3.5f;  }
    else             { l = -3.30f; s = 6.2f;  }
    const float s2 = s * s;
    const int f = c >> 1;
    const float* act = (f == 0) ? na_v : (f == 1) ? na_a : na_m;
    const int tid = threadIdx.x;

    for (int idx = tid; idx < 9216; idx += 256) {
        int j = idx / 96, k = idx - j * 96;
        int d = abs(j - k); d = min(d, 96 - d);
        G[j][k]     = __expf(-0.5f * (float)(d * d) * s2);
        act_s[j][k] = act[idx];
    }
    __syncthreads();

    const int hg3 = (tid >> 3) * 3;   // 32 groups of 3 rows
    const int jl3 = (tid & 7) * 3;    // 8 groups of 3 cols (within stripe)

    // stage 1: T1[h, js+j] = sum_k act[h,k] * G[js+j,k]
    float t1[3][3] = {};
    for (int k0 = 0; k0 < 96; k0 += 4) {
        float4 av[3], gv[3];
        #pragma unroll
        for (int r = 0; r < 3; r++) {
            av[r] = *(const float4*)&act_s[hg3 + r][k0];
            gv[r] = *(const float4*)&G[js + jl3 + r][k0];
        }
        #pragma unroll
        for (int hh = 0; hh < 3; hh++)
            #pragma unroll
            for (int jj = 0; jj < 3; jj++)
                t1[hh][jj] += av[hh].x * gv[jj].x + av[hh].y * gv[jj].y
                            + av[hh].z * gv[jj].z + av[hh].w * gv[jj].w;
    }
    #pragma unroll
    for (int hh = 0; hh < 3; hh++)
        #pragma unroll
        for (int jj = 0; jj < 3; jj++)
            T1t[jl3 + jj][hg3 + hh] = t1[hh][jj];
    __syncthreads();

    // stage 2: out[i, js+j] = sum_h G[i,h] * T1t[j][h]
    float o[3][3] = {};
    for (int h0 = 0; h0 < 96; h0 += 4) {
        float4 gv[3], tv[3];
        #pragma unroll
        for (int r = 0; r < 3; r++) {
            gv[r] = *(const float4*)&G[hg3 + r][h0];
            tv[r] = *(const float4*)&T1t[jl3 + r][h0];
        }
        #pragma unroll
        for (int ii = 0; ii < 3; ii++)
            #pragma unroll
            for (int jj = 0; jj < 3; jj++)
                o[ii][jj] += gv[ii].x * tv[jj].x + gv[ii].y * tv[jj].y
                           + gv[ii].z * tv[jj].z + gv[ii].w * tv[jj].w;
    }
    #pragma unroll
    for (int ii = 0; ii < 3; ii++)
        #pragma unroll
        for (int jj = 0; jj < 3; jj++)
            cpt[c * NPOS + (hg3 + ii) * 96 + (js + jl3 + jj)] = l * o[ii][jj];
}

// ---------------- ext GEMMs: C[b,p] = sum_k src[b,k] * rf[p,k] ----------------
// One thread = one position, 32 batch accumulators; src chunk in LDS (broadcast
// reads), rf streamed from global with a 2-group-deep explicit pipeline.
__global__ __launch_bounds__(256, 4) void ext_kernel(
    const float* __restrict__ video, const float* __restrict__ audio,
    const float* __restrict__ rf_v, const float* __restrict__ rf_a,
    float* __restrict__ ws, int kch, int nblk_v, int parta_off)
{
    extern __shared__ float A[];   // [kch][32]
    const int bid = blockIdx.x;
    const float* src; const float* rf; float* part; int K;
    int chunk, ptile;
    if (bid < nblk_v) {
        chunk = bid / NPT; ptile = bid - chunk * NPT;
        src = video; rf = rf_v; K = KV;
        part = ws + (size_t)chunk * (BB * NPOS);
    } else {
        int idx = bid - nblk_v;
        chunk = idx / NPT; ptile = idx - chunk * NPT;
        src = audio; rf = rf_a; K = KA;
        part = ws + parta_off + (size_t)chunk * (BB * NPOS);
    }
    const int kbase = chunk * kch;
    const int tid = threadIdx.x;

    // stage A[k][b]: each thread loads kch/8 consecutive k of one batch row
    {
        const int b   = tid & 31;
        const int kpt = kch >> 3;
        const int kk0 = (tid >> 5) * kpt;
        const float* sp = src + (size_t)b * K + kbase + kk0;
        #pragma unroll 4
        for (int q = 0; q < kpt; q++) A[(kk0 + q) * 32 + b] = sp[q];
    }
    __syncthreads();

    const int p = ptile * PTILE + tid;
    const float4* bp = (const float4*)(rf + (size_t)p * K + kbase);
    float acc[32];
    #pragma unroll
    for (int b = 0; b < 32; b++) acc[b] = 0.f;

    const int ngr = kch >> 3;        // groups of 8 k
    float4 c0 = bp[0], c1 = bp[1];   // group g
    float4 n0 = bp[2], n1 = bp[3];   // group g+1
    for (int g = 0; g < ngr; ++g) {
        float4 m0 = n0, m1 = n1;     // group g+2 (prefetch)
        if (g + 2 < ngr) { m0 = bp[2 * g + 4]; m1 = bp[2 * g + 5]; }
        const float* Ak = &A[(g << 3) * 32];
        float ks[8] = {c0.x, c0.y, c0.z, c0.w, c1.x, c1.y, c1.z, c1.w};
        #pragma unroll
        for (int j = 0; j < 8; j++) {
            const float bk = ks[j];
            #pragma unroll
            for (int q = 0; q < 8; q++) {
                float4 av = *(const float4*)&Ak[j * 32 + q * 4];
                acc[q * 4 + 0] = fmaf(av.x, bk, acc[q * 4 + 0]);
                acc[q * 4 + 1] = fmaf(av.y, bk, acc[q * 4 + 1]);
                acc[q * 4 + 2] = fmaf(av.z, bk, acc[q * 4 + 2]);
                acc[q * 4 + 3] = fmaf(av.w, bk, acc[q * 4 + 3]);
            }
        }
        c0 = n0; c1 = n1; n0 = m0; n1 = m1;
    }
    #pragma unroll
    for (int b = 0; b < 32; b++) part[(size_t)b * NPOS + p] = acc[b];
}

// ---------------- combine: reduce partials + sigmoid dynamics ----------------
__global__ __launch_bounds__(256) void combine_kernel(
    const float* __restrict__ na_v, const float* __restrict__ na_a,
    const float* __restrict__ na_m, const float* __restrict__ ws,
    float* __restrict__ out, int nchv, int ncha, int parta_off, int cpt_off)
{
    const int npq = NPOS >> 2;                 // 2304 float4s per (b) row
    const int t = blockIdx.x * 256 + threadIdx.x;
    if (t >= BB * npq) return;
    const int b  = t / npq;
    const int p0 = (t - b * npq) << 2;

    float4 ev = {0.f, 0.f, 0.f, 0.f}, ea = {0.f, 0.f, 0.f, 0.f};
    for (int c = 0; c < nchv; c++) {
        float4 x = *(const float4*)&ws[(size_t)c * (BB * NPOS) + (size_t)b * NPOS + p0];
        ev.x += x.x; ev.y += x.y; ev.z += x.z; ev.w += x.w;
    }
    for (int c = 0; c < ncha; c++) {
        float4 x = *(const float4*)&ws[(size_t)parta_off + (size_t)c * (BB * NPOS) + (size_t)b * NPOS + p0];
        ea.x += x.x; ea.y += x.y; ea.z += x.z; ea.w += x.w;
    }
    const float* cpt = ws + cpt_off;
    float4 q0 = *(const float4*)&cpt[0 * NPOS + p0];
    float4 q1 = *(const float4*)&cpt[1 * NPOS + p0];
    float4 q2 = *(const float4*)&cpt[2 * NPOS + p0];
    float4 q3 = *(const float4*)&cpt[3 * NPOS + p0];
    float4 q4 = *(const float4*)&cpt[4 * NPOS + p0];
    float4 q5 = *(const float4*)&cpt[5 * NPOS + p0];
    float4 nv = *(const float4*)&na_v[p0];
    float4 na = *(const float4*)&na_a[p0];
    float4 nm = *(const float4*)&na_m[p0];

    float evs[4] = {ev.x, ev.y, ev.z, ev.w};
    float eas[4] = {ea.x, ea.y, ea.z, ea.w};
    float nbv[4] = {q0.x + q1.x, q0.y + q1.y, q0.z + q1.z, q0.w + q1.w};
    float nba[4] = {q2.x + q3.x, q2.y + q3.y, q2.z + q3.z, q2.w + q3.w};
    float nbm[4] = {q4.x + q5.x, q4.y + q5.y, q4.z + q5.z, q4.w + q5.w};
    float nvs[4] = {nv.x, nv.y, nv.z, nv.w};
    float nas[4] = {na.x, na.y, na.z, na.w};
    float nms[4] = {nm.x, nm.y, nm.z, nm.w};

    float4 o;
    float* os = (float*)&o;
    #pragma unroll
    for (int u = 0; u < 4; u++) {
        const float xv = (evs[u] + nbv[u] - 3.0f + nms[u]) * 0.3f;
        const float nav_new = nvs[u] * (2.f / 3.f) + (1.f / 3.f) / (1.f + __expf(-xv));
        const float xa = (eas[u] + nba[u] - 3.0f + nms[u]) * 0.3f;
        const float naa_new = nas[u] * (2.f / 3.f) + (1.f / 3.f) / (1.f + __expf(-xa));
        const float xm = (7.0f * nav_new + 3.0f * naa_new + nbm[u] - 3.0f) * 0.3f;
        os[u] = nms[u] * (2.f / 3.f) + (1.f / 3.f) / (1.f + __expf(-xm));
    }
    *(float4*)&out[(size_t)b * NPOS + p0] = o;
}

extern "C" void kernel_launch(void* const* d_in, const int* in_sizes, int n_in,
                              void* d_out, int out_size, void* d_ws, size_t ws_size,
                              hipStream_t stream) {
    const float* video = (const float*)d_in[0];
    const float* audio = (const float*)d_in[1];
    const float* rf_v  = (const float*)d_in[2];
    const float* rf_a  = (const float*)d_in[3];
    const float* na_v  = (const float*)d_in[4];
    const float* na_a  = (const float*)d_in[5];
    const float* na_m  = (const float*)d_in[6];
    float* ws  = (float*)d_ws;
    float* out = (float*)d_out;

    // KCH=128 needs (8+16)*BB*NPOS + 6*NPOS floats of ws; fall back to KCH=256.
    int kch, nchv, ncha;
    const size_t need128 = ((size_t)24 * BB * NPOS + 6 * NPOS) * sizeof(float);
    if (ws_size >= need128) { kch = 128; nchv = 8; ncha = 16; }
    else                    { kch = 256; nchv = 4; ncha = 8;  }
    const int parta_off = nchv * BB * NPOS;
    const int cpt_off   = parta_off + ncha * BB * NPOS;

    nb_kernel<<<24, 256, 0, stream>>>(na_v, na_a, na_m, ws + cpt_off);
    ext_kernel<<<(nchv + ncha) * NPT, 256, kch * 32 * 4, stream>>>(
        video, audio, rf_v, rf_a, ws, kch, nchv * NPT, parta_off);
    combine_kernel<<<(BB * NPOS / 4 + 255) / 256, 256, 0, stream>>>(
        na_v, na_a, na_m, ws, out, nchv, ncha, parta_off, cpt_off);
}